// Round 1
// 523.924 us; speedup vs baseline: 1.1293x; 1.1293x over previous
//
#include <hip/hip_runtime.h>
#include <math.h>

#define DD 128
// packed row: [e(128) | b(128) | s(128)] fp16 = 768 B
#define PSTRIDE 384

typedef _Float16 half8 __attribute__((ext_vector_type(8)));
typedef _Float16 half2v __attribute__((ext_vector_type(2)));
typedef float floatx4 __attribute__((ext_vector_type(4)));

__device__ __forceinline__ float wave_sum_f(float x) {
#pragma unroll
  for (int m = 32; m >= 1; m >>= 1) x += __shfl_xor(x, m, 64);
  return x;
}
__device__ __forceinline__ float g16_sum(float x) {
#pragma unroll
  for (int m = 8; m >= 1; m >>= 1) x += __shfl_xor(x, m, 64);
  return x;
}
__device__ __forceinline__ int wave_sum_i(int x) {
#pragma unroll
  for (int m = 32; m >= 1; m >>= 1) x += __shfl_xor(x, m, 64);
  return x;
}

__global__ void degrees_kernel(const int* __restrict__ src, const int* __restrict__ dst,
                               int* __restrict__ out_deg, int* __restrict__ in_deg, int E) {
  int e = blockIdx.x * blockDim.x + threadIdx.x;
  if (e < E) {
    atomicAdd(&out_deg[src[e]], 1);
    atomicAdd(&in_deg[dst[e]], 1);
  }
}

__global__ void norms_kernel(const int* __restrict__ in_deg, const int* __restrict__ out_deg,
                             float* __restrict__ norm_in, float* __restrict__ norm_out,
                             float* __restrict__ inv_in, int N) {
  int i = blockIdx.x * blockDim.x + threadIdx.x;
  if (i < N) {
    int di = in_deg[i], dq = out_deg[i];
    norm_in[i]  = di > 0 ? 1.0f / sqrtf((float)di) : 0.0f;
    norm_out[i] = dq > 0 ? 1.0f / sqrtf((float)dq) : 0.0f;
    inv_in[i]   = di > 0 ? 1.0f / (float)di : 0.0f;
  }
}

// ---- 3-phase scan of in_deg -> row_off (exclusive) ----
__global__ void part_sum_kernel(const int* __restrict__ deg, int* __restrict__ part, int N) {
  __shared__ int wsum[4];
  int t = threadIdx.x, lane = t & 63, w = t >> 6;
  int i = blockIdx.x * 256 + t;
  int x = (i < N) ? deg[i] : 0;
  int s = wave_sum_i(x);
  if (lane == 0) wsum[w] = s;
  __syncthreads();
  if (t == 0) part[blockIdx.x] = wsum[0] + wsum[1] + wsum[2] + wsum[3];
}

__global__ void part_scan_kernel(int* __restrict__ part, int nb) {
  __shared__ int wsum[4];
  int t = threadIdx.x, lane = t & 63, w = t >> 6;
  int x = (t < nb) ? part[t] : 0;
  int v = x;
#pragma unroll
  for (int off = 1; off < 64; off <<= 1) {
    int y = __shfl_up(v, off, 64);
    if (lane >= off) v += y;
  }
  if (lane == 63) wsum[w] = v;
  __syncthreads();
  int base = 0;
  for (int j = 0; j < w; ++j) base += wsum[j];
  if (t < nb) part[t] = base + v - x;  // exclusive
}

__global__ void local_scan_kernel(const int* __restrict__ deg, const int* __restrict__ part,
                                  int* __restrict__ row_off, int N, int E) {
  __shared__ int wsum[4];
  int t = threadIdx.x, lane = t & 63, w = t >> 6;
  int i = blockIdx.x * 256 + t;
  int x = (i < N) ? deg[i] : 0;
  int v = x;
#pragma unroll
  for (int off = 1; off < 64; off <<= 1) {
    int y = __shfl_up(v, off, 64);
    if (lane >= off) v += y;
  }
  if (lane == 63) wsum[w] = v;
  __syncthreads();
  int base = 0;
  for (int j = 0; j < w; ++j) base += wsum[j];
  if (i < N) row_off[i] = part[blockIdx.x] + base + v - x;
  if (blockIdx.x == 0 && t == 0) row_off[N] = E;
}

// CSR fill: store {src, norm_out[src]} fused so agg needs no dependent gather
__global__ void csr_fill_kernel(const int* __restrict__ src, const int* __restrict__ dst,
                                const float* __restrict__ norm_out,
                                const int* __restrict__ row_off, int* __restrict__ cursor,
                                int2* __restrict__ csr_sw, int E) {
  int e = blockIdx.x * blockDim.x + threadIdx.x;
  if (e < E) {
    int d = dst[e], s = src[e];
    int pos = row_off[d] + atomicAdd(&cursor[d], 1);
    csr_sw[pos] = make_int2(s, __float_as_int(norm_out[s]));
  }
}

// fp32 -> fp16 bulk convert for the 3 contiguous W blocks (whE|whB|whS)
__global__ void wcvt3_kernel(const float* __restrict__ a, const float* __restrict__ b,
                             const float* __restrict__ c, _Float16* __restrict__ o, int n) {
  int i = blockIdx.x * 256 + threadIdx.x;
  if (i < n) {
    o[i]         = (_Float16)a[i];
    o[i + n]     = (_Float16)b[i];
    o[i + 2 * n] = (_Float16)c[i];
  }
}

// Fused: pack e/b/s fp32 rows into P (fp16) + compute initial logmap/l2 scales.
// One wave per node.
__global__ void pack_init_kernel(const float* __restrict__ e0, const float* __restrict__ b0,
                                 const float* __restrict__ s0, _Float16* __restrict__ P,
                                 float* __restrict__ sb, float* __restrict__ ss, int N) {
  int lane = threadIdx.x & 63;
  int v = blockIdx.x * 4 + (threadIdx.x >> 6);
  if (v >= N) return;
  size_t ri = (size_t)v * 64 + lane;
  float2 e2 = ((const float2*)e0)[ri];
  float2 b2 = ((const float2*)b0)[ri];
  float2 s2 = ((const float2*)s0)[ri];
  _Float16* Pr = P + (size_t)v * PSTRIDE + lane * 2;
  half2v he; he.x = (_Float16)e2.x; he.y = (_Float16)e2.y;
  half2v hb; hb.x = (_Float16)b2.x; hb.y = (_Float16)b2.y;
  half2v hs; hs.x = (_Float16)s2.x; hs.y = (_Float16)s2.y;
  *(half2v*)&Pr[0]   = he;
  *(half2v*)&Pr[128] = hb;
  *(half2v*)&Pr[256] = hs;
  float nb = sqrtf(wave_sum_f(b2.x * b2.x + b2.y * b2.y));
  float ns = sqrtf(wave_sum_f(s2.x * s2.x + s2.y * s2.y));
  if (lane == 0) {
    float ncb = fminf(fmaxf(nb, 1e-7f), 1.0f - 1e-5f);
    sb[v] = atanhf(ncb) / fmaxf(nb, 1e-7f);
    ss[v] = 1.0f / fmaxf(ns, 1e-12f);
  }
}

// MFMA fp16 GEMM for all 3 parts in one launch (blockIdx.y = part).
// part 0 (e): post = identity; part 1/2 (b/s): post = scale[v]*acc + bias[c]
// Block: 64 rows x 128 cols, K=128 fully staged in LDS, one barrier.
__global__ __launch_bounds__(256) void gemm3_kernel(const _Float16* __restrict__ P,
                                                    const _Float16* __restrict__ WhE,
                                                    const _Float16* __restrict__ WhB,
                                                    const _Float16* __restrict__ WhS,
                                                    const float* __restrict__ bBl,
                                                    const float* __restrict__ sBl,
                                                    const float* __restrict__ sbv,
                                                    const float* __restrict__ ssv,
                                                    _Float16* __restrict__ Qout, int N) {
  __shared__ _Float16 As[64 * 136];
  __shared__ _Float16 Ws[128 * 136];
  int part = blockIdx.y;
  const _Float16* Ain = P + part * DD;
  const _Float16* Wh = (part == 0) ? WhE : (part == 1 ? WhB : WhS);
  const float* Bb = (part == 1) ? bBl : sBl;
  const float* scv = (part == 1) ? sbv : ssv;
  _Float16* Qo = Qout + part * DD;
  int t = threadIdx.x;
  int rbase = blockIdx.x * 64;

  // stage W (fp16, pad 136 to break power-of-2 bank stride)
#pragma unroll
  for (int i = 0; i < 8; ++i) {
    int idx = i * 256 + t;                 // 16B chunk id
    int row = idx >> 4, col = (idx & 15) * 8;
    *(half8*)&Ws[row * 136 + col] = *(const half8*)&Wh[idx * 8];
  }
  // stage A: 4 threads per row, 32 halves each
  {
    int ar = t >> 2, aseg = t & 3;
    int av = rbase + ar; if (av >= N) av = N - 1;
    const _Float16* Ap = Ain + (size_t)av * PSTRIDE + aseg * 32;
    _Float16* Ad = &As[ar * 136 + aseg * 32];
    *(half8*)&Ad[0]  = *(const half8*)&Ap[0];
    *(half8*)&Ad[8]  = *(const half8*)&Ap[8];
    *(half8*)&Ad[16] = *(const half8*)&Ap[16];
    *(half8*)&Ad[24] = *(const half8*)&Ap[24];
  }
  __syncthreads();

  int lane = t & 63, w = t >> 6;
  int m = lane & 15, quad = lane >> 4;
  int c0 = w * 32;

  // B-frags: lane holds W[c0+16*tj+m][kk*32+quad*8 .. +7]
  half8 bf[2][4];
#pragma unroll
  for (int tj = 0; tj < 2; ++tj)
#pragma unroll
    for (int kk = 0; kk < 4; ++kk)
      bf[tj][kk] = *(const half8*)&Ws[(c0 + tj * 16 + m) * 136 + kk * 32 + quad * 8];

  float bias0 = 0.f, bias1 = 0.f;
  if (part) { bias0 = Bb[c0 + m]; bias1 = Bb[c0 + 16 + m]; }

#pragma unroll
  for (int r = 0; r < 4; ++r) {
    int row0 = r * 16;
    floatx4 acc0 = {0.f, 0.f, 0.f, 0.f}, acc1 = {0.f, 0.f, 0.f, 0.f};
#pragma unroll
    for (int kk = 0; kk < 4; ++kk) {
      half8 af = *(const half8*)&As[(row0 + m) * 136 + kk * 32 + quad * 8];
      acc0 = __builtin_amdgcn_mfma_f32_16x16x32_f16(af, bf[0][kk], acc0, 0, 0, 0);
      acc1 = __builtin_amdgcn_mfma_f32_16x16x32_f16(af, bf[1][kk], acc1, 0, 0, 0);
    }
    // C/D layout: col = lane&15, row = quad*4 + reg
    int vrow = rbase + row0 + quad * 4;
#pragma unroll
    for (int reg = 0; reg < 4; ++reg) {
      int v = vrow + reg;
      if (v < N) {
        float x0 = acc0[reg], x1 = acc1[reg];
        if (part) { float s = scv[v]; x0 = x0 * s + bias0; x1 = x1 * s + bias1; }
        Qo[(size_t)v * PSTRIDE + c0 + m]      = (_Float16)x0;
        Qo[(size_t)v * PSTRIDE + c0 + 16 + m] = (_Float16)x1;
      }
    }
  }
}

// Fused gather over packed Q: one wave per dst node.
// Lane = 16*g + q : group g handles neighbor slot i+g, lane loads 16B (dims 8q..8q+7).
// One load instruction moves 1 KB (4 neighbors' part-rows) vs 256 B before.
__global__ __launch_bounds__(256) void agg_fused_kernel(
    const _Float16* __restrict__ Q, const int* __restrict__ row_off,
    const int2* __restrict__ csr_sw, const float* __restrict__ norm_in,
    const float* __restrict__ inv_in, const float* __restrict__ eBias,
    float* __restrict__ oe, float* __restrict__ ob, float* __restrict__ os,
    _Float16* __restrict__ Pnext, float* __restrict__ sb, float* __restrict__ ss,
    int N, int write_pack, int write_out) {
  int lane = threadIdx.x & 63;
  int v = blockIdx.x * 4 + (threadIdx.x >> 6);
  if (v >= N) return;
  int g = lane >> 4, q = lane & 15;
  int beg = row_off[v], end = row_off[v + 1];
  float eacc[8], bacc[8], sacc[8];
#pragma unroll
  for (int j = 0; j < 8; ++j) { eacc[j] = 0.f; bacc[j] = 0.f; sacc[j] = 0.f; }
  int i = beg;
  // main: 8 neighbors per iter (2 per group), 6 x 16B gathers in flight
  for (; i + 8 <= end; i += 8) {
    int2 swa = csr_sw[i + g];
    int2 swb = csr_sw[i + 4 + g];
    float wa = __int_as_float(swa.y), wb = __int_as_float(swb.y);
    const _Float16* ra = Q + (size_t)swa.x * PSTRIDE + q * 8;
    const _Float16* rb = Q + (size_t)swb.x * PSTRIDE + q * 8;
    half8 ea = *(const half8*)ra;
    half8 e2 = *(const half8*)rb;
    half8 ba = *(const half8*)(ra + 128);
    half8 b2 = *(const half8*)(rb + 128);
    half8 sa = *(const half8*)(ra + 256);
    half8 s2 = *(const half8*)(rb + 256);
#pragma unroll
    for (int j = 0; j < 8; ++j) {
      eacc[j] += wa * (float)ea[j];
      eacc[j] += wb * (float)e2[j];
      bacc[j] += (float)ba[j];
      bacc[j] += (float)b2[j];
      sacc[j] += (float)sa[j];
      sacc[j] += (float)s2[j];
    }
  }
  if (i + 4 <= end) {  // 4-neighbor step
    int2 sw = csr_sw[i + g];
    float wgt = __int_as_float(sw.y);
    const _Float16* rp = Q + (size_t)sw.x * PSTRIDE + q * 8;
    half8 ev = *(const half8*)rp;
    half8 bv = *(const half8*)(rp + 128);
    half8 sv = *(const half8*)(rp + 256);
#pragma unroll
    for (int j = 0; j < 8; ++j) {
      eacc[j] += wgt * (float)ev[j];
      bacc[j] += (float)bv[j];
      sacc[j] += (float)sv[j];
    }
    i += 4;
  }
  if (i + g < end) {   // tail (<4): only groups with a neighbor left
    int2 sw = csr_sw[i + g];
    float wgt = __int_as_float(sw.y);
    const _Float16* rp = Q + (size_t)sw.x * PSTRIDE + q * 8;
    half8 ev = *(const half8*)rp;
    half8 bv = *(const half8*)(rp + 128);
    half8 sv = *(const half8*)(rp + 256);
#pragma unroll
    for (int j = 0; j < 8; ++j) {
      eacc[j] += wgt * (float)ev[j];
      bacc[j] += (float)bv[j];
      sacc[j] += (float)sv[j];
    }
  }
  // combine the 4 neighbor-groups (lanes q, q+16, q+32, q+48)
#pragma unroll
  for (int j = 0; j < 8; ++j) {
    eacc[j] += __shfl_xor(eacc[j], 16, 64);
    eacc[j] += __shfl_xor(eacc[j], 32, 64);
    bacc[j] += __shfl_xor(bacc[j], 16, 64);
    bacc[j] += __shfl_xor(bacc[j], 32, 64);
    sacc[j] += __shfl_xor(sacc[j], 16, 64);
    sacc[j] += __shfl_xor(sacc[j], 32, 64);
  }
  float ni = norm_in[v], iv = inv_in[v];
  const float4* ebp = (const float4*)eBias;
  float4 eb0 = ebp[q * 2], eb1 = ebp[q * 2 + 1];
  float bias[8] = {eb0.x, eb0.y, eb0.z, eb0.w, eb1.x, eb1.y, eb1.z, eb1.w};
  float h[8], obv[8], osv[8];
  float bs2 = 0.f, ss2 = 0.f;
#pragma unroll
  for (int j = 0; j < 8; ++j) {
    float t = eacc[j] * ni + bias[j];
    h[j] = t > 0.f ? t : 0.2f * t;
    float ub = bacc[j] * iv; obv[j] = ub; bs2 += ub * ub;
    float us = sacc[j] * iv; osv[j] = us; ss2 += us * us;
  }
  float nb = sqrtf(g16_sum(bs2));
  float ns = sqrtf(g16_sum(ss2));
  float fb = tanhf(nb) / fmaxf(nb, 1e-7f);   // expmap0
  float fs = 1.0f / fmaxf(ns, 1e-12f);       // l2norm
#pragma unroll
  for (int j = 0; j < 8; ++j) { obv[j] *= fb; osv[j] *= fs; }
  if (write_out) {  // final layer only: fp32 outputs, split across groups
    if (g == 0) {
      float4* p = (float4*)(oe + (size_t)v * DD);
      p[q * 2]     = make_float4(h[0], h[1], h[2], h[3]);
      p[q * 2 + 1] = make_float4(h[4], h[5], h[6], h[7]);
    } else if (g == 1) {
      float4* p = (float4*)(ob + (size_t)v * DD);
      p[q * 2]     = make_float4(obv[0], obv[1], obv[2], obv[3]);
      p[q * 2 + 1] = make_float4(obv[4], obv[5], obv[6], obv[7]);
    } else if (g == 2) {
      float4* p = (float4*)(os + (size_t)v * DD);
      p[q * 2]     = make_float4(osv[0], osv[1], osv[2], osv[3]);
      p[q * 2 + 1] = make_float4(osv[4], osv[5], osv[6], osv[7]);
    }
  }
  if (write_pack) {  // non-final layers: fp16 pack + next-layer scales
    if (g == 3) {
      half8 he, hb, hs;
#pragma unroll
      for (int j = 0; j < 8; ++j) {
        he[j] = (_Float16)h[j];
        hb[j] = (_Float16)obv[j];
        hs[j] = (_Float16)osv[j];
      }
      _Float16* Pr = Pnext + (size_t)v * PSTRIDE + q * 8;
      *(half8*)&Pr[0]   = he;
      *(half8*)&Pr[128] = hb;
      *(half8*)&Pr[256] = hs;
    }
    if (lane == 0) {
      float mb = fb * nb;
      float ncb = fminf(fmaxf(mb, 1e-7f), 1.0f - 1e-5f);
      sb[v] = atanhf(ncb) / fmaxf(mb, 1e-7f);
      float ms = fs * ns;
      ss[v] = 1.0f / fmaxf(ms, 1e-12f);
    }
  }
}

extern "C" void kernel_launch(void* const* d_in, const int* in_sizes, int n_in,
                              void* d_out, int out_size, void* d_ws, size_t ws_size,
                              hipStream_t stream) {
  const float* e0 = (const float*)d_in[0];
  const float* b0 = (const float*)d_in[1];
  const float* s0 = (const float*)d_in[2];
  const float* eW = (const float*)d_in[3];
  const float* eB = (const float*)d_in[4];
  const float* bW = (const float*)d_in[5];
  const float* bB = (const float*)d_in[6];
  const float* sW = (const float*)d_in[7];
  const float* sB = (const float*)d_in[8];
  const int* src = (const int*)d_in[9];
  const int* dst = (const int*)d_in[10];
  int N = in_sizes[0] / DD;
  int E = in_sizes[9];
  int L = in_sizes[3] / (DD * DD);
  int LDD2 = L * DD * DD;

  char* w = (char*)d_ws;
  int* in_deg  = (int*)w; w += (size_t)N * 4;
  int* out_deg = (int*)w; w += (size_t)N * 4;
  int* cursor  = (int*)w; w += (size_t)N * 4;
  int* row_off = (int*)w; w += (size_t)(N + 4) * 4;
  int* pscan   = (int*)w; w += (size_t)1024 * 4;
  int2* csr_sw = (int2*)w; w += (size_t)E * 8;
  float* norm_in  = (float*)w; w += (size_t)N * 4;
  float* norm_out = (float*)w; w += (size_t)N * 4;
  float* inv_in   = (float*)w; w += (size_t)N * 4;
  float* sb       = (float*)w; w += (size_t)N * 4;
  float* ss       = (float*)w; w += (size_t)N * 4;
  _Float16* P     = (_Float16*)w; w += (size_t)N * PSTRIDE * 2;
  _Float16* Q     = (_Float16*)w; w += (size_t)N * PSTRIDE * 2;
  _Float16* whE   = (_Float16*)w; w += (size_t)LDD2 * 2;
  _Float16* whB   = (_Float16*)w; w += (size_t)LDD2 * 2;
  _Float16* whS   = (_Float16*)w; w += (size_t)LDD2 * 2;

  float* oe = (float*)d_out;
  float* ob = oe + (size_t)N * DD;
  float* os = ob + (size_t)N * DD;

  int PB = (N + 255) / 256;
  int AB = (N + 3) / 4;
  int GB = (N + 63) / 64;

  hipMemsetAsync(d_ws, 0, (size_t)3 * N * 4, stream);  // in_deg,out_deg,cursor
  degrees_kernel<<<(E + 255) / 256, 256, 0, stream>>>(src, dst, out_deg, in_deg, E);
  norms_kernel<<<(N + 255) / 256, 256, 0, stream>>>(in_deg, out_deg, norm_in, norm_out, inv_in, N);
  part_sum_kernel<<<PB, 256, 0, stream>>>(in_deg, pscan, N);
  part_scan_kernel<<<1, 256, 0, stream>>>(pscan, PB);
  local_scan_kernel<<<PB, 256, 0, stream>>>(in_deg, pscan, row_off, N, E);
  csr_fill_kernel<<<(E + 255) / 256, 256, 0, stream>>>(src, dst, norm_out, row_off, cursor, csr_sw, E);
  wcvt3_kernel<<<(LDD2 + 255) / 256, 256, 0, stream>>>(eW, bW, sW, whE, LDD2);
  pack_init_kernel<<<AB, 256, 0, stream>>>(e0, b0, s0, P, sb, ss, N);

  for (int l = 0; l < L; ++l) {
    size_t lo = (size_t)l * DD * DD;
    gemm3_kernel<<<dim3(GB, 3), 256, 0, stream>>>(P, whE + lo, whB + lo, whS + lo,
                                                  bB + (size_t)l * DD, sB + (size_t)l * DD,
                                                  sb, ss, Q, N);
    agg_fused_kernel<<<AB, 256, 0, stream>>>(Q, row_off, csr_sw, norm_in, inv_in,
                                             eB + (size_t)l * DD, oe, ob, os, P, sb, ss, N,
                                             (l < L - 1) ? 1 : 0, (l == L - 1) ? 1 : 0);
  }
}

// Round 2
// 496.206 us; speedup vs baseline: 1.1924x; 1.0559x over previous
//
#include <hip/hip_runtime.h>
#include <math.h>

#define DD 128
// packed row: [e(128) | b(128) | s(128)] fp16 = 768 B
#define PSTRIDE 384

typedef _Float16 half8 __attribute__((ext_vector_type(8)));
typedef _Float16 half2v __attribute__((ext_vector_type(2)));
typedef float floatx4 __attribute__((ext_vector_type(4)));

__device__ __forceinline__ float wave_sum_f(float x) {
#pragma unroll
  for (int m = 32; m >= 1; m >>= 1) x += __shfl_xor(x, m, 64);
  return x;
}
__device__ __forceinline__ float g16_sum(float x) {
#pragma unroll
  for (int m = 8; m >= 1; m >>= 1) x += __shfl_xor(x, m, 64);
  return x;
}
__device__ __forceinline__ int wave_sum_i(int x) {
#pragma unroll
  for (int m = 32; m >= 1; m >>= 1) x += __shfl_xor(x, m, 64);
  return x;
}

// ---- fused first launch: degrees atomics || pack+scale init || W fp16 convert ----
// (independent workloads; atomic-latency-bound blocks overlap with streaming blocks)
__global__ void setup_fused_kernel(const int* __restrict__ src, const int* __restrict__ dst,
                                   int* __restrict__ out_deg, int* __restrict__ in_deg, int E,
                                   const float* __restrict__ e0, const float* __restrict__ b0,
                                   const float* __restrict__ s0, _Float16* __restrict__ P, int N,
                                   const float* __restrict__ eW, const float* __restrict__ bW,
                                   const float* __restrict__ sW, _Float16* __restrict__ Wh, int nW,
                                   int DB, int AB) {
  int bx = blockIdx.x;
  if (bx < DB) {  // degrees
    int e = bx * 256 + threadIdx.x;
    if (e < E) {
      atomicAdd(&out_deg[src[e]], 1);
      atomicAdd(&in_deg[dst[e]], 1);
    }
  } else if (bx < DB + AB) {  // pack e/b/s -> P with pre-transform scales applied
    int lane = threadIdx.x & 63;
    int v = (bx - DB) * 4 + (threadIdx.x >> 6);
    if (v >= N) return;
    size_t ri = (size_t)v * 64 + lane;
    float2 e2 = ((const float2*)e0)[ri];
    float2 b2 = ((const float2*)b0)[ri];
    float2 s2 = ((const float2*)s0)[ri];
    float nb = sqrtf(wave_sum_f(b2.x * b2.x + b2.y * b2.y));
    float ns = sqrtf(wave_sum_f(s2.x * s2.x + s2.y * s2.y));
    float ncb = fminf(fmaxf(nb, 1e-7f), 1.0f - 1e-5f);
    float fb = atanhf(ncb) / fmaxf(nb, 1e-7f);  // logmap0 scale
    float fs = 1.0f / fmaxf(ns, 1e-12f);        // l2norm scale
    _Float16* Pr = P + (size_t)v * PSTRIDE + lane * 2;
    half2v he; he.x = (_Float16)e2.x;        he.y = (_Float16)e2.y;
    half2v hb; hb.x = (_Float16)(b2.x * fb); hb.y = (_Float16)(b2.y * fb);
    half2v hs; hs.x = (_Float16)(s2.x * fs); hs.y = (_Float16)(s2.y * fs);
    *(half2v*)&Pr[0]   = he;
    *(half2v*)&Pr[128] = hb;
    *(half2v*)&Pr[256] = hs;
  } else {  // W convert, 3 contiguous blocks [eW | bW | sW]
    int i = (bx - DB - AB) * 256 + threadIdx.x;
    if (i < nW) {
      Wh[i]          = (_Float16)eW[i];
      Wh[i + nW]     = (_Float16)bW[i];
      Wh[i + 2 * nW] = (_Float16)sW[i];
    }
  }
}

// norms (elementwise) + per-block partial sums of in_deg, one launch
__global__ void norms_psum_kernel(const int* __restrict__ in_deg, const int* __restrict__ out_deg,
                                  float* __restrict__ norm_in, float* __restrict__ norm_out,
                                  float* __restrict__ inv_in, int* __restrict__ part, int N) {
  __shared__ int wsum[4];
  int t = threadIdx.x, lane = t & 63, w = t >> 6;
  int i = blockIdx.x * 256 + t;
  int di = 0;
  if (i < N) {
    di = in_deg[i];
    int dq = out_deg[i];
    norm_in[i]  = di > 0 ? 1.0f / sqrtf((float)di) : 0.0f;
    norm_out[i] = dq > 0 ? 1.0f / sqrtf((float)dq) : 0.0f;
    inv_in[i]   = di > 0 ? 1.0f / (float)di : 0.0f;
  }
  int s = wave_sum_i(di);
  if (lane == 0) wsum[w] = s;
  __syncthreads();
  if (t == 0) part[blockIdx.x] = wsum[0] + wsum[1] + wsum[2] + wsum[3];
}

__global__ void part_scan_kernel(int* __restrict__ part, int nb) {
  __shared__ int wsum[4];
  int t = threadIdx.x, lane = t & 63, w = t >> 6;
  int x = (t < nb) ? part[t] : 0;
  int v = x;
#pragma unroll
  for (int off = 1; off < 64; off <<= 1) {
    int y = __shfl_up(v, off, 64);
    if (lane >= off) v += y;
  }
  if (lane == 63) wsum[w] = v;
  __syncthreads();
  int base = 0;
  for (int j = 0; j < w; ++j) base += wsum[j];
  if (t < nb) part[t] = base + v - x;  // exclusive
}

__global__ void local_scan_kernel(const int* __restrict__ deg, const int* __restrict__ part,
                                  int* __restrict__ row_off, int N, int E) {
  __shared__ int wsum[4];
  int t = threadIdx.x, lane = t & 63, w = t >> 6;
  int i = blockIdx.x * 256 + t;
  int x = (i < N) ? deg[i] : 0;
  int v = x;
#pragma unroll
  for (int off = 1; off < 64; off <<= 1) {
    int y = __shfl_up(v, off, 64);
    if (lane >= off) v += y;
  }
  if (lane == 63) wsum[w] = v;
  __syncthreads();
  int base = 0;
  for (int j = 0; j < w; ++j) base += wsum[j];
  if (i < N) row_off[i] = part[blockIdx.x] + base + v - x;
  if (blockIdx.x == 0 && t == 0) row_off[N] = E;
}

// ---- LDS-free MFMA GEMM tile: 64 rows x 128 cols, K=128 ----
// A and W fragments loaded directly from global: lanes {m, m+16, m+32, m+48}
// cover one contiguous 64B segment per row -> perfectly coalesced; A has zero
// block-level reuse so LDS staging was pure overhead; W is L2-hot (782-block reuse).
__device__ __forceinline__ void gemm_tile(int part, int rb, const _Float16* __restrict__ P,
                                          const _Float16* __restrict__ Wh,
                                          const float* __restrict__ Bb,
                                          _Float16* __restrict__ Q, int N) {
  int t = threadIdx.x, lane = t & 63, w = t >> 6;
  int m = lane & 15, quad = lane >> 4, c0 = w * 32;
  int rbase = rb * 64;
  const _Float16* Ain = P + part * DD;
  _Float16* Qo = Q + part * DD;
  half8 bf[2][4];
#pragma unroll
  for (int tj = 0; tj < 2; ++tj)
#pragma unroll
    for (int kk = 0; kk < 4; ++kk)
      bf[tj][kk] = *(const half8*)&Wh[(c0 + tj * 16 + m) * DD + kk * 32 + quad * 8];
  float bias0 = 0.f, bias1 = 0.f;
  if (Bb) { bias0 = Bb[c0 + m]; bias1 = Bb[c0 + 16 + m]; }
#pragma unroll
  for (int r = 0; r < 4; ++r) {
    int row0 = r * 16;
    int arow = rbase + row0 + m; if (arow >= N) arow = N - 1;
    const _Float16* Ap = Ain + (size_t)arow * PSTRIDE;
    floatx4 acc0 = {0.f, 0.f, 0.f, 0.f}, acc1 = {0.f, 0.f, 0.f, 0.f};
#pragma unroll
    for (int kk = 0; kk < 4; ++kk) {
      half8 af = *(const half8*)&Ap[kk * 32 + quad * 8];
      acc0 = __builtin_amdgcn_mfma_f32_16x16x32_f16(af, bf[0][kk], acc0, 0, 0, 0);
      acc1 = __builtin_amdgcn_mfma_f32_16x16x32_f16(af, bf[1][kk], acc1, 0, 0, 0);
    }
    // C/D layout: col = lane&15, row = quad*4 + reg
    int vrow = rbase + row0 + quad * 4;
#pragma unroll
    for (int reg = 0; reg < 4; ++reg) {
      int v = vrow + reg;
      if (v < N) {
        Qo[(size_t)v * PSTRIDE + c0 + m]      = (_Float16)(acc0[reg] + bias0);
        Qo[(size_t)v * PSTRIDE + c0 + 16 + m] = (_Float16)(acc1[reg] + bias1);
      }
    }
  }
}

// csr_fill (random scatter, latency-bound) || layer-0 GEMM (MFMA-bound) in one launch
__global__ __launch_bounds__(256) void fill_gemm_kernel(
    const int* __restrict__ src, const int* __restrict__ dst,
    const float* __restrict__ norm_out, const int* __restrict__ row_off,
    int* __restrict__ cursor, int2* __restrict__ csr_sw, int E,
    const _Float16* __restrict__ P, const _Float16* __restrict__ WhE,
    const _Float16* __restrict__ WhB, const _Float16* __restrict__ WhS,
    const float* __restrict__ bBl, const float* __restrict__ sBl,
    _Float16* __restrict__ Q, int N, int FB, int GB) {
  int bx = blockIdx.x;
  if (bx < FB) {  // csr fill first (longest pole starts earliest)
    int e = bx * 256 + threadIdx.x;
    if (e < E) {
      int d = dst[e], s = src[e];
      int pos = row_off[d] + atomicAdd(&cursor[d], 1);
      csr_sw[pos] = make_int2(s, __float_as_int(norm_out[s]));
    }
  } else {
    int gb = bx - FB;
    int part = gb / GB, rb = gb % GB;
    const _Float16* Wh = (part == 0) ? WhE : (part == 1 ? WhB : WhS);
    const float* Bb = (part == 0) ? nullptr : (part == 1 ? bBl : sBl);
    gemm_tile(part, rb, P, Wh, Bb, Q, N);
  }
}

// standalone GEMM for layers >= 1
__global__ __launch_bounds__(256) void gemm3_kernel(const _Float16* __restrict__ P,
                                                    const _Float16* __restrict__ WhE,
                                                    const _Float16* __restrict__ WhB,
                                                    const _Float16* __restrict__ WhS,
                                                    const float* __restrict__ bBl,
                                                    const float* __restrict__ sBl,
                                                    _Float16* __restrict__ Q, int N) {
  int part = blockIdx.y;
  const _Float16* Wh = (part == 0) ? WhE : (part == 1 ? WhB : WhS);
  const float* Bb = (part == 0) ? nullptr : (part == 1 ? bBl : sBl);
  gemm_tile(part, blockIdx.x, P, Wh, Bb, Q, N);
}

// Fused gather over packed Q: one wave per dst node.
// Lane = 16*g + q : group g handles neighbor slot i+g, lane loads 16B (dims 8q..8q+7).
// b-branch carries the tangent mean directly (logmap0∘expmap0 = id); s-branch's
// l2norm is idempotent -> next layer consumes packed values with no extra scale.
__global__ __launch_bounds__(256) void agg_fused_kernel(
    const _Float16* __restrict__ Q, const int* __restrict__ row_off,
    const int2* __restrict__ csr_sw, const float* __restrict__ norm_in,
    const float* __restrict__ inv_in, const float* __restrict__ eBias,
    float* __restrict__ oe, float* __restrict__ ob, float* __restrict__ os,
    _Float16* __restrict__ Pnext, int N, int write_pack, int write_out) {
  int lane = threadIdx.x & 63;
  int v = blockIdx.x * 4 + (threadIdx.x >> 6);
  if (v >= N) return;
  int g = lane >> 4, q = lane & 15;
  int beg = row_off[v], end = row_off[v + 1];
  float eacc[8], bacc[8], sacc[8];
#pragma unroll
  for (int j = 0; j < 8; ++j) { eacc[j] = 0.f; bacc[j] = 0.f; sacc[j] = 0.f; }
  int i = beg;
  for (; i + 8 <= end; i += 8) {  // 8 neighbors/iter, 6 x 16B gathers in flight
    int2 swa = csr_sw[i + g];
    int2 swb = csr_sw[i + 4 + g];
    float wa = __int_as_float(swa.y), wb = __int_as_float(swb.y);
    const _Float16* ra = Q + (size_t)swa.x * PSTRIDE + q * 8;
    const _Float16* rb = Q + (size_t)swb.x * PSTRIDE + q * 8;
    half8 ea = *(const half8*)ra;
    half8 e2 = *(const half8*)rb;
    half8 ba = *(const half8*)(ra + 128);
    half8 b2 = *(const half8*)(rb + 128);
    half8 sa = *(const half8*)(ra + 256);
    half8 s2 = *(const half8*)(rb + 256);
#pragma unroll
    for (int j = 0; j < 8; ++j) {
      eacc[j] += wa * (float)ea[j];
      eacc[j] += wb * (float)e2[j];
      bacc[j] += (float)ba[j];
      bacc[j] += (float)b2[j];
      sacc[j] += (float)sa[j];
      sacc[j] += (float)s2[j];
    }
  }
  if (i + 4 <= end) {
    int2 sw = csr_sw[i + g];
    float wgt = __int_as_float(sw.y);
    const _Float16* rp = Q + (size_t)sw.x * PSTRIDE + q * 8;
    half8 ev = *(const half8*)rp;
    half8 bv = *(const half8*)(rp + 128);
    half8 sv = *(const half8*)(rp + 256);
#pragma unroll
    for (int j = 0; j < 8; ++j) {
      eacc[j] += wgt * (float)ev[j];
      bacc[j] += (float)bv[j];
      sacc[j] += (float)sv[j];
    }
    i += 4;
  }
  if (i + g < end) {
    int2 sw = csr_sw[i + g];
    float wgt = __int_as_float(sw.y);
    const _Float16* rp = Q + (size_t)sw.x * PSTRIDE + q * 8;
    half8 ev = *(const half8*)rp;
    half8 bv = *(const half8*)(rp + 128);
    half8 sv = *(const half8*)(rp + 256);
#pragma unroll
    for (int j = 0; j < 8; ++j) {
      eacc[j] += wgt * (float)ev[j];
      bacc[j] += (float)bv[j];
      sacc[j] += (float)sv[j];
    }
  }
#pragma unroll
  for (int j = 0; j < 8; ++j) {  // combine 4 neighbor-groups
    eacc[j] += __shfl_xor(eacc[j], 16, 64);
    eacc[j] += __shfl_xor(eacc[j], 32, 64);
    bacc[j] += __shfl_xor(bacc[j], 16, 64);
    bacc[j] += __shfl_xor(bacc[j], 32, 64);
    sacc[j] += __shfl_xor(sacc[j], 16, 64);
    sacc[j] += __shfl_xor(sacc[j], 32, 64);
  }
  float ni = norm_in[v], iv = inv_in[v];
  const float4* ebp = (const float4*)eBias;
  float4 eb0 = ebp[q * 2], eb1 = ebp[q * 2 + 1];
  float bias[8] = {eb0.x, eb0.y, eb0.z, eb0.w, eb1.x, eb1.y, eb1.z, eb1.w};
  float h[8], ub[8], us[8];
  float ss2 = 0.f;
#pragma unroll
  for (int j = 0; j < 8; ++j) {
    float t = eacc[j] * ni + bias[j];
    h[j] = t > 0.f ? t : 0.2f * t;
    ub[j] = bacc[j] * iv;                 // tangent mean (b)
    us[j] = sacc[j] * iv; ss2 += us[j] * us[j];
  }
  float ns = sqrtf(g16_sum(ss2));
  float fs = 1.0f / fmaxf(ns, 1e-12f);    // l2norm scale (always needed)
  if (write_out) {  // final layer: fp32 outputs, split across lane-groups
    float bs2 = 0.f;
#pragma unroll
    for (int j = 0; j < 8; ++j) bs2 += ub[j] * ub[j];
    float nb = sqrtf(g16_sum(bs2));
    float fb = tanhf(nb) / fmaxf(nb, 1e-7f);  // expmap0
    if (g == 0) {
      float4* p = (float4*)(oe + (size_t)v * DD);
      p[q * 2]     = make_float4(h[0], h[1], h[2], h[3]);
      p[q * 2 + 1] = make_float4(h[4], h[5], h[6], h[7]);
    } else if (g == 1) {
      float4* p = (float4*)(ob + (size_t)v * DD);
      p[q * 2]     = make_float4(ub[0] * fb, ub[1] * fb, ub[2] * fb, ub[3] * fb);
      p[q * 2 + 1] = make_float4(ub[4] * fb, ub[5] * fb, ub[6] * fb, ub[7] * fb);
    } else if (g == 2) {
      float4* p = (float4*)(os + (size_t)v * DD);
      p[q * 2]     = make_float4(us[0] * fs, us[1] * fs, us[2] * fs, us[3] * fs);
      p[q * 2 + 1] = make_float4(us[4] * fs, us[5] * fs, us[6] * fs, us[7] * fs);
    }
  }
  if (write_pack) {  // non-final layers: fp16 pack only (no scales needed downstream)
    if (g == 3) {
      half8 he, hb, hs;
#pragma unroll
      for (int j = 0; j < 8; ++j) {
        he[j] = (_Float16)h[j];
        hb[j] = (_Float16)ub[j];
        hs[j] = (_Float16)(us[j] * fs);
      }
      _Float16* Pr = Pnext + (size_t)v * PSTRIDE + q * 8;
      *(half8*)&Pr[0]   = he;
      *(half8*)&Pr[128] = hb;
      *(half8*)&Pr[256] = hs;
    }
  }
}

extern "C" void kernel_launch(void* const* d_in, const int* in_sizes, int n_in,
                              void* d_out, int out_size, void* d_ws, size_t ws_size,
                              hipStream_t stream) {
  const float* e0 = (const float*)d_in[0];
  const float* b0 = (const float*)d_in[1];
  const float* s0 = (const float*)d_in[2];
  const float* eW = (const float*)d_in[3];
  const float* eB = (const float*)d_in[4];
  const float* bW = (const float*)d_in[5];
  const float* bB = (const float*)d_in[6];
  const float* sW = (const float*)d_in[7];
  const float* sB = (const float*)d_in[8];
  const int* src = (const int*)d_in[9];
  const int* dst = (const int*)d_in[10];
  int N = in_sizes[0] / DD;
  int E = in_sizes[9];
  int L = in_sizes[3] / (DD * DD);
  int LDD2 = L * DD * DD;

  char* w = (char*)d_ws;
  int* in_deg  = (int*)w; w += (size_t)N * 4;
  int* out_deg = (int*)w; w += (size_t)N * 4;
  int* cursor  = (int*)w; w += (size_t)N * 4;
  int* row_off = (int*)w; w += (size_t)(N + 4) * 4;
  int* pscan   = (int*)w; w += (size_t)1024 * 4;
  int2* csr_sw = (int2*)w; w += (size_t)E * 8;
  float* norm_in  = (float*)w; w += (size_t)N * 4;
  float* norm_out = (float*)w; w += (size_t)N * 4;
  float* inv_in   = (float*)w; w += (size_t)N * 4;
  w = (char*)(((size_t)w + 255) & ~(size_t)255);  // align
  _Float16* P = (_Float16*)w; w += (size_t)N * PSTRIDE * 2;
  _Float16* Q = (_Float16*)w; w += (size_t)N * PSTRIDE * 2;
  _Float16* Wh = (_Float16*)w; w += (size_t)3 * LDD2 * 2;
  _Float16* whE = Wh;
  _Float16* whB = Wh + LDD2;
  _Float16* whS = Wh + 2 * LDD2;

  float* oe = (float*)d_out;
  float* ob = oe + (size_t)N * DD;
  float* os = ob + (size_t)N * DD;

  int DB = (E + 255) / 256;
  int AB = (N + 3) / 4;
  int GB = (N + 63) / 64;
  int WB = (LDD2 + 255) / 256;
  int PB = (N + 255) / 256;

  hipMemsetAsync(d_ws, 0, (size_t)3 * N * 4, stream);  // in_deg,out_deg,cursor
  setup_fused_kernel<<<DB + AB + WB, 256, 0, stream>>>(src, dst, out_deg, in_deg, E,
                                                       e0, b0, s0, P, N,
                                                       eW, bW, sW, Wh, LDD2, DB, AB);
  norms_psum_kernel<<<PB, 256, 0, stream>>>(in_deg, out_deg, norm_in, norm_out, inv_in, pscan, N);
  part_scan_kernel<<<1, 256, 0, stream>>>(pscan, PB);
  local_scan_kernel<<<PB, 256, 0, stream>>>(in_deg, pscan, row_off, N, E);
  fill_gemm_kernel<<<DB + 3 * GB, 256, 0, stream>>>(src, dst, norm_out, row_off, cursor, csr_sw, E,
                                                    P, whE, whB, whS, bB, sB, Q, N, DB, GB);
  agg_fused_kernel<<<AB, 256, 0, stream>>>(Q, row_off, csr_sw, norm_in, inv_in, eB,
                                           oe, ob, os, P, N,
                                           (L > 1) ? 1 : 0, (L == 1) ? 1 : 0);
  for (int l = 1; l < L; ++l) {
    size_t lo = (size_t)l * DD * DD;
    gemm3_kernel<<<dim3(GB, 3), 256, 0, stream>>>(P, whE + lo, whB + lo, whS + lo,
                                                  bB + (size_t)l * DD, sB + (size_t)l * DD, Q, N);
    agg_fused_kernel<<<AB, 256, 0, stream>>>(Q, row_off, csr_sw, norm_in, inv_in,
                                             eB + (size_t)l * DD, oe, ob, os, P, N,
                                             (l < L - 1) ? 1 : 0, (l == L - 1) ? 1 : 0);
  }
}

// Round 3
// 494.197 us; speedup vs baseline: 1.1973x; 1.0041x over previous
//
#include <hip/hip_runtime.h>
#include <math.h>

#define DD 128
// packed row: [e(128) | b(128) | s(128)] fp16 = 768 B
#define PSTRIDE 384

typedef _Float16 half8 __attribute__((ext_vector_type(8)));
typedef float floatx4 __attribute__((ext_vector_type(4)));

__device__ __forceinline__ float g16_sum(float x) {
#pragma unroll
  for (int m = 8; m >= 1; m >>= 1) x += __shfl_xor(x, m, 64);
  return x;
}
__device__ __forceinline__ int wave_sum_i(int x) {
#pragma unroll
  for (int m = 32; m >= 1; m >>= 1) x += __shfl_xor(x, m, 64);
  return x;
}

// ---- K1: degree atomics (8-way bin-spread to kill same-line contention) || W fp16 convert ----
__global__ void deg_wcvt_kernel(const int* __restrict__ src, const int* __restrict__ dst,
                                int* __restrict__ out_deg8, int* __restrict__ in_deg8,
                                int E, int N,
                                const float* __restrict__ eW, const float* __restrict__ bW,
                                const float* __restrict__ sW, _Float16* __restrict__ Wh, int nW,
                                int DB) {
  int bx = blockIdx.x;
  if (bx < DB) {
    int e = bx * 256 + threadIdx.x;
    if (e < E) {
      // bin varies across waves so concurrent ops on one node hit different lines
      int h = ((bx << 2) + (threadIdx.x >> 6)) & 7;
      atomicAdd(&out_deg8[h * N + src[e]], 1);
      atomicAdd(&in_deg8[h * N + dst[e]], 1);
    }
  } else {
    int i = (bx - DB) * 256 + threadIdx.x;
    if (i < nW) {
      Wh[i]          = (_Float16)eW[i];
      Wh[i + nW]     = (_Float16)bW[i];
      Wh[i + 2 * nW] = (_Float16)sW[i];
    }
  }
}

// K2: reduce 8 bins -> degrees, norms, and per-block partial sums of in_deg
__global__ void norms_psum_kernel(const int* __restrict__ in_deg8, const int* __restrict__ out_deg8,
                                  int* __restrict__ in_deg, float* __restrict__ norm_in,
                                  float* __restrict__ norm_out, float* __restrict__ inv_in,
                                  int* __restrict__ part, int N) {
  __shared__ int wsum[4];
  int t = threadIdx.x, lane = t & 63, w = t >> 6;
  int i = blockIdx.x * 256 + t;
  int di = 0;
  if (i < N) {
    int dq = 0;
#pragma unroll
    for (int h = 0; h < 8; ++h) {
      di += in_deg8[h * N + i];
      dq += out_deg8[h * N + i];
    }
    in_deg[i] = di;
    norm_in[i]  = di > 0 ? 1.0f / sqrtf((float)di) : 0.0f;
    norm_out[i] = dq > 0 ? 1.0f / sqrtf((float)dq) : 0.0f;
    inv_in[i]   = di > 0 ? 1.0f / (float)di : 0.0f;
  }
  int s = wave_sum_i(di);
  if (lane == 0) wsum[w] = s;
  __syncthreads();
  if (t == 0) part[blockIdx.x] = wsum[0] + wsum[1] + wsum[2] + wsum[3];
}

__global__ void part_scan_kernel(int* __restrict__ part, int nb) {
  __shared__ int wsum[4];
  int t = threadIdx.x, lane = t & 63, w = t >> 6;
  int x = (t < nb) ? part[t] : 0;
  int v = x;
#pragma unroll
  for (int off = 1; off < 64; off <<= 1) {
    int y = __shfl_up(v, off, 64);
    if (lane >= off) v += y;
  }
  if (lane == 63) wsum[w] = v;
  __syncthreads();
  int base = 0;
  for (int j = 0; j < w; ++j) base += wsum[j];
  if (t < nb) part[t] = base + v - x;  // exclusive
}

__global__ void local_scan_kernel(const int* __restrict__ deg, const int* __restrict__ part,
                                  int* __restrict__ row_off, int N, int E) {
  __shared__ int wsum[4];
  int t = threadIdx.x, lane = t & 63, w = t >> 6;
  int i = blockIdx.x * 256 + t;
  int x = (i < N) ? deg[i] : 0;
  int v = x;
#pragma unroll
  for (int off = 1; off < 64; off <<= 1) {
    int y = __shfl_up(v, off, 64);
    if (lane >= off) v += y;
  }
  if (lane == 63) wsum[w] = v;
  __syncthreads();
  int base = 0;
  for (int j = 0; j < w; ++j) base += wsum[j];
  if (i < N) row_off[i] = part[blockIdx.x] + base + v - x;
  if (blockIdx.x == 0 && t == 0) row_off[N] = E;
}

// ---- layer-0 GEMM tile: A read fp32 DIRECTLY from e0/b0/s0 (no pack pass) ----
// Per-row norm computed in-register (16 lanes sharing m hold the full row);
// scale applied to the accumulator (linearity: (f*row)@W = f*(row@W)).
__device__ __forceinline__ void gemm0_tile(int part, int rb, const float* __restrict__ A,
                                           const _Float16* __restrict__ Wh,
                                           const float* __restrict__ Bb,
                                           _Float16* __restrict__ Q, int N) {
  int t = threadIdx.x, lane = t & 63, w = t >> 6;
  int m = lane & 15, quad = lane >> 4, c0 = w * 32;
  int rbase = rb * 64;
  _Float16* Qo = Q + part * DD;
  half8 bf[2][4];
#pragma unroll
  for (int tj = 0; tj < 2; ++tj)
#pragma unroll
    for (int kk = 0; kk < 4; ++kk)
      bf[tj][kk] = *(const half8*)&Wh[(c0 + tj * 16 + m) * DD + kk * 32 + quad * 8];
  float bias0 = 0.f, bias1 = 0.f;
  if (part) { bias0 = Bb[c0 + m]; bias1 = Bb[c0 + 16 + m]; }
#pragma unroll
  for (int r = 0; r < 4; ++r) {
    int row0 = r * 16;
    int arow = rbase + row0 + m; if (arow >= N) arow = N - 1;
    const float* Ap = A + (size_t)arow * DD;
    half8 af[4];
    float nsq = 0.f;
#pragma unroll
    for (int kk = 0; kk < 4; ++kk) {
      float4 x0 = *(const float4*)&Ap[kk * 32 + quad * 8];
      float4 x1 = *(const float4*)&Ap[kk * 32 + quad * 8 + 4];
      if (part)
        nsq += x0.x * x0.x + x0.y * x0.y + x0.z * x0.z + x0.w * x0.w +
               x1.x * x1.x + x1.y * x1.y + x1.z * x1.z + x1.w * x1.w;
      half8 a;
      a[0] = (_Float16)x0.x; a[1] = (_Float16)x0.y; a[2] = (_Float16)x0.z; a[3] = (_Float16)x0.w;
      a[4] = (_Float16)x1.x; a[5] = (_Float16)x1.y; a[6] = (_Float16)x1.z; a[7] = (_Float16)x1.w;
      af[kk] = a;
    }
    float fr = 1.f;
    if (part) {  // full-row norm: combine the 4 quad slices
      nsq += __shfl_xor(nsq, 16, 64);
      nsq += __shfl_xor(nsq, 32, 64);
      float n = sqrtf(nsq);
      if (part == 1) {  // logmap0 scale
        float nc = fminf(fmaxf(n, 1e-7f), 1.0f - 1e-5f);
        fr = atanhf(nc) / fmaxf(n, 1e-7f);
      } else {          // l2norm scale
        fr = 1.0f / fmaxf(n, 1e-12f);
      }
    }
    floatx4 acc0 = {0.f, 0.f, 0.f, 0.f}, acc1 = {0.f, 0.f, 0.f, 0.f};
#pragma unroll
    for (int kk = 0; kk < 4; ++kk) {
      acc0 = __builtin_amdgcn_mfma_f32_16x16x32_f16(af[kk], bf[0][kk], acc0, 0, 0, 0);
      acc1 = __builtin_amdgcn_mfma_f32_16x16x32_f16(af[kk], bf[1][kk], acc1, 0, 0, 0);
    }
    // C/D layout: col = lane&15, row = quad*4 + reg. Scale lives on lane (m = quad*4+reg).
    int vrow = rbase + row0 + quad * 4;
#pragma unroll
    for (int reg = 0; reg < 4; ++reg) {
      int v = vrow + reg;
      float fs = part ? __shfl(fr, quad * 4 + reg, 64) : 1.f;
      if (v < N) {
        Qo[(size_t)v * PSTRIDE + c0 + m]      = (_Float16)(acc0[reg] * fs + bias0);
        Qo[(size_t)v * PSTRIDE + c0 + 16 + m] = (_Float16)(acc1[reg] * fs + bias1);
      }
    }
  }
}

// ---- fp16 GEMM tile for layers >= 1 (A = packed P written by agg; no scales needed:
// b carries tangent mean directly (logmap0∘expmap0=id), s already normalized) ----
__device__ __forceinline__ void gemm_tile(int part, int rb, const _Float16* __restrict__ P,
                                          const _Float16* __restrict__ Wh,
                                          const float* __restrict__ Bb,
                                          _Float16* __restrict__ Q, int N) {
  int t = threadIdx.x, lane = t & 63, w = t >> 6;
  int m = lane & 15, quad = lane >> 4, c0 = w * 32;
  int rbase = rb * 64;
  const _Float16* Ain = P + part * DD;
  _Float16* Qo = Q + part * DD;
  half8 bf[2][4];
#pragma unroll
  for (int tj = 0; tj < 2; ++tj)
#pragma unroll
    for (int kk = 0; kk < 4; ++kk)
      bf[tj][kk] = *(const half8*)&Wh[(c0 + tj * 16 + m) * DD + kk * 32 + quad * 8];
  float bias0 = 0.f, bias1 = 0.f;
  if (Bb) { bias0 = Bb[c0 + m]; bias1 = Bb[c0 + 16 + m]; }
#pragma unroll
  for (int r = 0; r < 4; ++r) {
    int row0 = r * 16;
    int arow = rbase + row0 + m; if (arow >= N) arow = N - 1;
    const _Float16* Ap = Ain + (size_t)arow * PSTRIDE;
    floatx4 acc0 = {0.f, 0.f, 0.f, 0.f}, acc1 = {0.f, 0.f, 0.f, 0.f};
#pragma unroll
    for (int kk = 0; kk < 4; ++kk) {
      half8 af = *(const half8*)&Ap[kk * 32 + quad * 8];
      acc0 = __builtin_amdgcn_mfma_f32_16x16x32_f16(af, bf[0][kk], acc0, 0, 0, 0);
      acc1 = __builtin_amdgcn_mfma_f32_16x16x32_f16(af, bf[1][kk], acc1, 0, 0, 0);
    }
    int vrow = rbase + row0 + quad * 4;
#pragma unroll
    for (int reg = 0; reg < 4; ++reg) {
      int v = vrow + reg;
      if (v < N) {
        Qo[(size_t)v * PSTRIDE + c0 + m]      = (_Float16)(acc0[reg] + bias0);
        Qo[(size_t)v * PSTRIDE + c0 + 16 + m] = (_Float16)(acc1[reg] + bias1);
      }
    }
  }
}

// K5: csr_fill (random scatter, latency-bound) || layer-0 GEMM (MFMA-bound)
__global__ __launch_bounds__(256) void fill_gemm0_kernel(
    const int* __restrict__ src, const int* __restrict__ dst,
    const float* __restrict__ norm_out, const int* __restrict__ row_off,
    int* __restrict__ cursor, int2* __restrict__ csr_sw, int E,
    const float* __restrict__ e0, const float* __restrict__ b0, const float* __restrict__ s0,
    const _Float16* __restrict__ WhE, const _Float16* __restrict__ WhB,
    const _Float16* __restrict__ WhS, const float* __restrict__ bBl,
    const float* __restrict__ sBl, _Float16* __restrict__ Q, int N, int FB, int GB) {
  int bx = blockIdx.x;
  if (bx < FB) {  // csr fill first (longest pole starts earliest)
    int e = bx * 256 + threadIdx.x;
    if (e < E) {
      int d = dst[e], s = src[e];
      int pos = row_off[d] + atomicAdd(&cursor[d], 1);
      csr_sw[pos] = make_int2(s, __float_as_int(norm_out[s]));
    }
  } else {
    int gb = bx - FB;
    int part = gb / GB, rb = gb % GB;
    const float* A = (part == 0) ? e0 : (part == 1 ? b0 : s0);
    const _Float16* Wh = (part == 0) ? WhE : (part == 1 ? WhB : WhS);
    const float* Bb = (part == 0) ? nullptr : (part == 1 ? bBl : sBl);
    gemm0_tile(part, rb, A, Wh, Bb, Q, N);
  }
}

// standalone fp16 GEMM for layers >= 1
__global__ __launch_bounds__(256) void gemm3_kernel(const _Float16* __restrict__ P,
                                                    const _Float16* __restrict__ WhE,
                                                    const _Float16* __restrict__ WhB,
                                                    const _Float16* __restrict__ WhS,
                                                    const float* __restrict__ bBl,
                                                    const float* __restrict__ sBl,
                                                    _Float16* __restrict__ Q, int N) {
  int part = blockIdx.y;
  const _Float16* Wh = (part == 0) ? WhE : (part == 1 ? WhB : WhS);
  const float* Bb = (part == 0) ? nullptr : (part == 1 ? bBl : sBl);
  gemm_tile(part, blockIdx.x, P, Wh, Bb, Q, N);
}

// Fused gather over packed Q: one wave per dst node.
// Lane = 16*g + q : group g handles neighbor slot i+g, lane loads 16B (dims 8q..8q+7).
__global__ __launch_bounds__(256) void agg_fused_kernel(
    const _Float16* __restrict__ Q, const int* __restrict__ row_off,
    const int2* __restrict__ csr_sw, const float* __restrict__ norm_in,
    const float* __restrict__ inv_in, const float* __restrict__ eBias,
    float* __restrict__ oe, float* __restrict__ ob, float* __restrict__ os,
    _Float16* __restrict__ Pnext, int N, int write_pack, int write_out) {
  int lane = threadIdx.x & 63;
  int v = blockIdx.x * 4 + (threadIdx.x >> 6);
  if (v >= N) return;
  int g = lane >> 4, q = lane & 15;
  int beg = row_off[v], end = row_off[v + 1];
  float eacc[8], bacc[8], sacc[8];
#pragma unroll
  for (int j = 0; j < 8; ++j) { eacc[j] = 0.f; bacc[j] = 0.f; sacc[j] = 0.f; }
  int i = beg;
  for (; i + 8 <= end; i += 8) {  // 8 neighbors/iter, 6 x 16B gathers in flight
    int2 swa = csr_sw[i + g];
    int2 swb = csr_sw[i + 4 + g];
    float wa = __int_as_float(swa.y), wb = __int_as_float(swb.y);
    const _Float16* ra = Q + (size_t)swa.x * PSTRIDE + q * 8;
    const _Float16* rb = Q + (size_t)swb.x * PSTRIDE + q * 8;
    half8 ea = *(const half8*)ra;
    half8 e2 = *(const half8*)rb;
    half8 ba = *(const half8*)(ra + 128);
    half8 b2 = *(const half8*)(rb + 128);
    half8 sa = *(const half8*)(ra + 256);
    half8 s2 = *(const half8*)(rb + 256);
#pragma unroll
    for (int j = 0; j < 8; ++j) {
      eacc[j] += wa * (float)ea[j];
      eacc[j] += wb * (float)e2[j];
      bacc[j] += (float)ba[j];
      bacc[j] += (float)b2[j];
      sacc[j] += (float)sa[j];
      sacc[j] += (float)s2[j];
    }
  }
  if (i + 4 <= end) {
    int2 sw = csr_sw[i + g];
    float wgt = __int_as_float(sw.y);
    const _Float16* rp = Q + (size_t)sw.x * PSTRIDE + q * 8;
    half8 ev = *(const half8*)rp;
    half8 bv = *(const half8*)(rp + 128);
    half8 sv = *(const half8*)(rp + 256);
#pragma unroll
    for (int j = 0; j < 8; ++j) {
      eacc[j] += wgt * (float)ev[j];
      bacc[j] += (float)bv[j];
      sacc[j] += (float)sv[j];
    }
    i += 4;
  }
  if (i + g < end) {
    int2 sw = csr_sw[i + g];
    float wgt = __int_as_float(sw.y);
    const _Float16* rp = Q + (size_t)sw.x * PSTRIDE + q * 8;
    half8 ev = *(const half8*)rp;
    half8 bv = *(const half8*)(rp + 128);
    half8 sv = *(const half8*)(rp + 256);
#pragma unroll
    for (int j = 0; j < 8; ++j) {
      eacc[j] += wgt * (float)ev[j];
      bacc[j] += (float)bv[j];
      sacc[j] += (float)sv[j];
    }
  }
#pragma unroll
  for (int j = 0; j < 8; ++j) {  // combine 4 neighbor-groups
    eacc[j] += __shfl_xor(eacc[j], 16, 64);
    eacc[j] += __shfl_xor(eacc[j], 32, 64);
    bacc[j] += __shfl_xor(bacc[j], 16, 64);
    bacc[j] += __shfl_xor(bacc[j], 32, 64);
    sacc[j] += __shfl_xor(sacc[j], 16, 64);
    sacc[j] += __shfl_xor(sacc[j], 32, 64);
  }
  float ni = norm_in[v], iv = inv_in[v];
  const float4* ebp = (const float4*)eBias;
  float4 eb0 = ebp[q * 2], eb1 = ebp[q * 2 + 1];
  float bias[8] = {eb0.x, eb0.y, eb0.z, eb0.w, eb1.x, eb1.y, eb1.z, eb1.w};
  float h[8], ub[8], us[8];
  float ss2 = 0.f;
#pragma unroll
  for (int j = 0; j < 8; ++j) {
    float t = eacc[j] * ni + bias[j];
    h[j] = t > 0.f ? t : 0.2f * t;
    ub[j] = bacc[j] * iv;                 // tangent mean (b)
    us[j] = sacc[j] * iv; ss2 += us[j] * us[j];
  }
  float ns = sqrtf(g16_sum(ss2));
  float fs = 1.0f / fmaxf(ns, 1e-12f);    // l2norm scale
  if (write_out) {  // final layer: fp32 outputs, split across lane-groups
    float bs2 = 0.f;
#pragma unroll
    for (int j = 0; j < 8; ++j) bs2 += ub[j] * ub[j];
    float nb = sqrtf(g16_sum(bs2));
    float fb = tanhf(nb) / fmaxf(nb, 1e-7f);  // expmap0
    if (g == 0) {
      float4* p = (float4*)(oe + (size_t)v * DD);
      p[q * 2]     = make_float4(h[0], h[1], h[2], h[3]);
      p[q * 2 + 1] = make_float4(h[4], h[5], h[6], h[7]);
    } else if (g == 1) {
      float4* p = (float4*)(ob + (size_t)v * DD);
      p[q * 2]     = make_float4(ub[0] * fb, ub[1] * fb, ub[2] * fb, ub[3] * fb);
      p[q * 2 + 1] = make_float4(ub[4] * fb, ub[5] * fb, ub[6] * fb, ub[7] * fb);
    } else if (g == 2) {
      float4* p = (float4*)(os + (size_t)v * DD);
      p[q * 2]     = make_float4(us[0] * fs, us[1] * fs, us[2] * fs, us[3] * fs);
      p[q * 2 + 1] = make_float4(us[4] * fs, us[5] * fs, us[6] * fs, us[7] * fs);
    }
  }
  if (write_pack) {  // non-final layers: fp16 pack only
    if (g == 3) {
      half8 he, hb, hs;
#pragma unroll
      for (int j = 0; j < 8; ++j) {
        he[j] = (_Float16)h[j];
        hb[j] = (_Float16)ub[j];
        hs[j] = (_Float16)(us[j] * fs);
      }
      _Float16* Pr = Pnext + (size_t)v * PSTRIDE + q * 8;
      *(half8*)&Pr[0]   = he;
      *(half8*)&Pr[128] = hb;
      *(half8*)&Pr[256] = hs;
    }
  }
}

extern "C" void kernel_launch(void* const* d_in, const int* in_sizes, int n_in,
                              void* d_out, int out_size, void* d_ws, size_t ws_size,
                              hipStream_t stream) {
  const float* e0 = (const float*)d_in[0];
  const float* b0 = (const float*)d_in[1];
  const float* s0 = (const float*)d_in[2];
  const float* eW = (const float*)d_in[3];
  const float* eB = (const float*)d_in[4];
  const float* bW = (const float*)d_in[5];
  const float* bB = (const float*)d_in[6];
  const float* sW = (const float*)d_in[7];
  const float* sB = (const float*)d_in[8];
  const int* src = (const int*)d_in[9];
  const int* dst = (const int*)d_in[10];
  int N = in_sizes[0] / DD;
  int E = in_sizes[9];
  int L = in_sizes[3] / (DD * DD);
  int LDD2 = L * DD * DD;

  char* w = (char*)d_ws;
  // [in_deg8 | out_deg8 | cursor] contiguous -> single memset
  int* in_deg8  = (int*)w; w += (size_t)8 * N * 4;
  int* out_deg8 = (int*)w; w += (size_t)8 * N * 4;
  int* cursor   = (int*)w; w += (size_t)N * 4;
  int* in_deg   = (int*)w; w += (size_t)N * 4;
  int* row_off  = (int*)w; w += (size_t)(N + 4) * 4;
  int* pscan    = (int*)w; w += (size_t)1024 * 4;
  int2* csr_sw  = (int2*)w; w += (size_t)E * 8;
  float* norm_in  = (float*)w; w += (size_t)N * 4;
  float* norm_out = (float*)w; w += (size_t)N * 4;
  float* inv_in   = (float*)w; w += (size_t)N * 4;
  w = (char*)(((size_t)w + 255) & ~(size_t)255);  // align
  _Float16* P = (_Float16*)w; w += (size_t)N * PSTRIDE * 2;
  _Float16* Q = (_Float16*)w; w += (size_t)N * PSTRIDE * 2;
  _Float16* Wh = (_Float16*)w; w += (size_t)3 * LDD2 * 2;
  _Float16* whE = Wh;
  _Float16* whB = Wh + LDD2;
  _Float16* whS = Wh + 2 * LDD2;

  float* oe = (float*)d_out;
  float* ob = oe + (size_t)N * DD;
  float* os = ob + (size_t)N * DD;

  int DB = (E + 255) / 256;
  int AB = (N + 3) / 4;
  int GB = (N + 63) / 64;
  int WB = (LDD2 + 255) / 256;
  int PB = (N + 255) / 256;

  hipMemsetAsync(d_ws, 0, (size_t)17 * N * 4, stream);  // deg bins + cursor
  deg_wcvt_kernel<<<DB + WB, 256, 0, stream>>>(src, dst, out_deg8, in_deg8, E, N,
                                               eW, bW, sW, Wh, LDD2, DB);
  norms_psum_kernel<<<PB, 256, 0, stream>>>(in_deg8, out_deg8, in_deg,
                                            norm_in, norm_out, inv_in, pscan, N);
  part_scan_kernel<<<1, 256, 0, stream>>>(pscan, PB);
  local_scan_kernel<<<PB, 256, 0, stream>>>(in_deg, pscan, row_off, N, E);
  fill_gemm0_kernel<<<DB + 3 * GB, 256, 0, stream>>>(src, dst, norm_out, row_off, cursor,
                                                     csr_sw, E, e0, b0, s0,
                                                     whE, whB, whS, bB, sB, Q, N, DB, GB);
  agg_fused_kernel<<<AB, 256, 0, stream>>>(Q, row_off, csr_sw, norm_in, inv_in, eB,
                                           oe, ob, os, P, N,
                                           (L > 1) ? 1 : 0, (L == 1) ? 1 : 0);
  for (int l = 1; l < L; ++l) {
    size_t lo = (size_t)l * DD * DD;
    gemm3_kernel<<<dim3(GB, 3), 256, 0, stream>>>(P, whE + lo, whB + lo, whS + lo,
                                                  bB + (size_t)l * DD, sB + (size_t)l * DD, Q, N);
    agg_fused_kernel<<<AB, 256, 0, stream>>>(Q, row_off, csr_sw, norm_in, inv_in,
                                             eB + (size_t)l * DD, oe, ob, os, P, N,
                                             (l < L - 1) ? 1 : 0, (l == L - 1) ? 1 : 0);
  }
}

// Round 4
// 482.193 us; speedup vs baseline: 1.2271x; 1.0249x over previous
//
#include <hip/hip_runtime.h>
#include <math.h>

#define DD 128
// packed row: [e(128) | b(128) | s(128)] fp16 = 768 B
#define PSTRIDE 384

typedef _Float16 half8 __attribute__((ext_vector_type(8)));
typedef float floatx4 __attribute__((ext_vector_type(4)));

__device__ __forceinline__ float g16_sum(float x) {
#pragma unroll
  for (int m = 8; m >= 1; m >>= 1) x += __shfl_xor(x, m, 64);
  return x;
}
__device__ __forceinline__ int wave_sum_i(int x) {
#pragma unroll
  for (int m = 32; m >= 1; m >>= 1) x += __shfl_xor(x, m, 64);
  return x;
}

// ---- K1: degree atomics (8-way bin spread) + edge rank capture || W fp16 convert ----
// The atomic return value IS the edge's rank within its (node, bin) -> csr_fill
// later needs no cursor atomic at all.
__global__ void deg_wcvt_kernel(const int* __restrict__ src, const int* __restrict__ dst,
                                int* __restrict__ out_deg8, int* __restrict__ in_deg8,
                                int* __restrict__ rank8, int E, int N,
                                const float* __restrict__ eW, const float* __restrict__ bW,
                                const float* __restrict__ sW, _Float16* __restrict__ Wh, int nW,
                                int DB) {
  int bx = blockIdx.x;
  if (bx < DB) {
    int e = bx * 256 + threadIdx.x;
    if (e < E) {
      int h = e & 7;  // bin: must match fill_gemm0's h for the same edge
      atomicAdd(&out_deg8[h * N + src[e]], 1);
      rank8[e] = atomicAdd(&in_deg8[h * N + dst[e]], 1);
    }
  } else {
    int i = (bx - DB) * 256 + threadIdx.x;
    if (i < nW) {
      Wh[i]          = (_Float16)eW[i];
      Wh[i + nW]     = (_Float16)bW[i];
      Wh[i + 2 * nW] = (_Float16)sW[i];
    }
  }
}

// K2: reduce 8 bins -> degrees, norms, and per-block partial sums of in_deg
__global__ void norms_psum_kernel(const int* __restrict__ in_deg8, const int* __restrict__ out_deg8,
                                  int* __restrict__ in_deg, float* __restrict__ norm_in,
                                  float* __restrict__ norm_out, float* __restrict__ inv_in,
                                  int* __restrict__ part, int N) {
  __shared__ int wsum[4];
  int t = threadIdx.x, lane = t & 63, w = t >> 6;
  int i = blockIdx.x * 256 + t;
  int di = 0;
  if (i < N) {
    int dq = 0;
#pragma unroll
    for (int h = 0; h < 8; ++h) {
      di += in_deg8[h * N + i];
      dq += out_deg8[h * N + i];
    }
    in_deg[i] = di;
    norm_in[i]  = di > 0 ? 1.0f / sqrtf((float)di) : 0.0f;
    norm_out[i] = dq > 0 ? 1.0f / sqrtf((float)dq) : 0.0f;
    inv_in[i]   = di > 0 ? 1.0f / (float)di : 0.0f;
  }
  int s = wave_sum_i(di);
  if (lane == 0) wsum[w] = s;
  __syncthreads();
  if (t == 0) part[blockIdx.x] = wsum[0] + wsum[1] + wsum[2] + wsum[3];
}

__global__ void part_scan_kernel(int* __restrict__ part, int nb) {
  __shared__ int wsum[4];
  int t = threadIdx.x, lane = t & 63, w = t >> 6;
  int x = (t < nb) ? part[t] : 0;
  int v = x;
#pragma unroll
  for (int off = 1; off < 64; off <<= 1) {
    int y = __shfl_up(v, off, 64);
    if (lane >= off) v += y;
  }
  if (lane == 63) wsum[w] = v;
  __syncthreads();
  int base = 0;
  for (int j = 0; j < w; ++j) base += wsum[j];
  if (t < nb) part[t] = base + v - x;  // exclusive
}

// K4: row_off scan + convert bin counts IN PLACE into absolute CSR base positions:
// in_deg8[h*N+i] := row_off[i] + sum_{h'<h} count[h'] -> fill needs ONE random read.
__global__ void local_scan_kernel(const int* __restrict__ deg, const int* __restrict__ part,
                                  int* __restrict__ row_off, int* __restrict__ in_deg8,
                                  int N, int E) {
  __shared__ int wsum[4];
  int t = threadIdx.x, lane = t & 63, w = t >> 6;
  int i = blockIdx.x * 256 + t;
  int x = (i < N) ? deg[i] : 0;
  int v = x;
#pragma unroll
  for (int off = 1; off < 64; off <<= 1) {
    int y = __shfl_up(v, off, 64);
    if (lane >= off) v += y;
  }
  if (lane == 63) wsum[w] = v;
  __syncthreads();
  int base = 0;
  for (int j = 0; j < w; ++j) base += wsum[j];
  if (i < N) {
    int ro = part[blockIdx.x] + base + v - x;
    row_off[i] = ro;
    int cum = ro;
#pragma unroll
    for (int h = 0; h < 8; ++h) {
      int c = in_deg8[h * N + i];
      in_deg8[h * N + i] = cum;
      cum += c;
    }
  }
  if (blockIdx.x == 0 && t == 0) row_off[N] = E;
}

// ---- layer-0 GEMM tile: A read fp32 DIRECTLY from e0/b0/s0 (no pack pass) ----
// Per-row norm computed in-register (16 lanes sharing m hold the full row);
// scale applied to the accumulator (linearity: (f*row)@W = f*(row@W)).
__device__ __forceinline__ void gemm0_tile(int part, int rb, const float* __restrict__ A,
                                           const _Float16* __restrict__ Wh,
                                           const float* __restrict__ Bb,
                                           _Float16* __restrict__ Q, int N) {
  int t = threadIdx.x, lane = t & 63, w = t >> 6;
  int m = lane & 15, quad = lane >> 4, c0 = w * 32;
  int rbase = rb * 64;
  _Float16* Qo = Q + part * DD;
  half8 bf[2][4];
#pragma unroll
  for (int tj = 0; tj < 2; ++tj)
#pragma unroll
    for (int kk = 0; kk < 4; ++kk)
      bf[tj][kk] = *(const half8*)&Wh[(c0 + tj * 16 + m) * DD + kk * 32 + quad * 8];
  float bias0 = 0.f, bias1 = 0.f;
  if (part) { bias0 = Bb[c0 + m]; bias1 = Bb[c0 + 16 + m]; }
#pragma unroll
  for (int r = 0; r < 4; ++r) {
    int row0 = r * 16;
    int arow = rbase + row0 + m; if (arow >= N) arow = N - 1;
    const float* Ap = A + (size_t)arow * DD;
    half8 af[4];
    float nsq = 0.f;
#pragma unroll
    for (int kk = 0; kk < 4; ++kk) {
      float4 x0 = *(const float4*)&Ap[kk * 32 + quad * 8];
      float4 x1 = *(const float4*)&Ap[kk * 32 + quad * 8 + 4];
      if (part)
        nsq += x0.x * x0.x + x0.y * x0.y + x0.z * x0.z + x0.w * x0.w +
               x1.x * x1.x + x1.y * x1.y + x1.z * x1.z + x1.w * x1.w;
      half8 a;
      a[0] = (_Float16)x0.x; a[1] = (_Float16)x0.y; a[2] = (_Float16)x0.z; a[3] = (_Float16)x0.w;
      a[4] = (_Float16)x1.x; a[5] = (_Float16)x1.y; a[6] = (_Float16)x1.z; a[7] = (_Float16)x1.w;
      af[kk] = a;
    }
    float fr = 1.f;
    if (part) {  // full-row norm: combine the 4 quad slices
      nsq += __shfl_xor(nsq, 16, 64);
      nsq += __shfl_xor(nsq, 32, 64);
      float n = sqrtf(nsq);
      if (part == 1) {  // logmap0 scale
        float nc = fminf(fmaxf(n, 1e-7f), 1.0f - 1e-5f);
        fr = atanhf(nc) / fmaxf(n, 1e-7f);
      } else {          // l2norm scale
        fr = 1.0f / fmaxf(n, 1e-12f);
      }
    }
    floatx4 acc0 = {0.f, 0.f, 0.f, 0.f}, acc1 = {0.f, 0.f, 0.f, 0.f};
#pragma unroll
    for (int kk = 0; kk < 4; ++kk) {
      acc0 = __builtin_amdgcn_mfma_f32_16x16x32_f16(af[kk], bf[0][kk], acc0, 0, 0, 0);
      acc1 = __builtin_amdgcn_mfma_f32_16x16x32_f16(af[kk], bf[1][kk], acc1, 0, 0, 0);
    }
    // C/D layout: col = lane&15, row = quad*4 + reg. Scale lives on lane (m = quad*4+reg).
    int vrow = rbase + row0 + quad * 4;
#pragma unroll
    for (int reg = 0; reg < 4; ++reg) {
      int v = vrow + reg;
      float fs = part ? __shfl(fr, quad * 4 + reg, 64) : 1.f;
      if (v < N) {
        Qo[(size_t)v * PSTRIDE + c0 + m]      = (_Float16)(acc0[reg] * fs + bias0);
        Qo[(size_t)v * PSTRIDE + c0 + 16 + m] = (_Float16)(acc1[reg] * fs + bias1);
      }
    }
  }
}

// ---- fp16 GEMM tile for layers >= 1 (A = packed P written by agg; no scales needed:
// b carries tangent mean directly (logmap0∘expmap0=id), s already normalized) ----
__device__ __forceinline__ void gemm_tile(int part, int rb, const _Float16* __restrict__ P,
                                          const _Float16* __restrict__ Wh,
                                          const float* __restrict__ Bb,
                                          _Float16* __restrict__ Q, int N) {
  int t = threadIdx.x, lane = t & 63, w = t >> 6;
  int m = lane & 15, quad = lane >> 4, c0 = w * 32;
  int rbase = rb * 64;
  const _Float16* Ain = P + part * DD;
  _Float16* Qo = Q + part * DD;
  half8 bf[2][4];
#pragma unroll
  for (int tj = 0; tj < 2; ++tj)
#pragma unroll
    for (int kk = 0; kk < 4; ++kk)
      bf[tj][kk] = *(const half8*)&Wh[(c0 + tj * 16 + m) * DD + kk * 32 + quad * 8];
  float bias0 = 0.f, bias1 = 0.f;
  if (Bb) { bias0 = Bb[c0 + m]; bias1 = Bb[c0 + 16 + m]; }
#pragma unroll
  for (int r = 0; r < 4; ++r) {
    int row0 = r * 16;
    int arow = rbase + row0 + m; if (arow >= N) arow = N - 1;
    const _Float16* Ap = Ain + (size_t)arow * PSTRIDE;
    floatx4 acc0 = {0.f, 0.f, 0.f, 0.f}, acc1 = {0.f, 0.f, 0.f, 0.f};
#pragma unroll
    for (int kk = 0; kk < 4; ++kk) {
      half8 af = *(const half8*)&Ap[kk * 32 + quad * 8];
      acc0 = __builtin_amdgcn_mfma_f32_16x16x32_f16(af, bf[0][kk], acc0, 0, 0, 0);
      acc1 = __builtin_amdgcn_mfma_f32_16x16x32_f16(af, bf[1][kk], acc1, 0, 0, 0);
    }
    int vrow = rbase + row0 + quad * 4;
#pragma unroll
    for (int reg = 0; reg < 4; ++reg) {
      int v = vrow + reg;
      if (v < N) {
        Qo[(size_t)v * PSTRIDE + c0 + m]      = (_Float16)(acc0[reg] + bias0);
        Qo[(size_t)v * PSTRIDE + c0 + 16 + m] = (_Float16)(acc1[reg] + bias1);
      }
    }
  }
}

// K5: atomic-free csr_fill (pos = bin_base[dst] + precomputed rank) || layer-0 GEMM
__global__ __launch_bounds__(256) void fill_gemm0_kernel(
    const int* __restrict__ src, const int* __restrict__ dst,
    const int* __restrict__ rank8, const int* __restrict__ bin_base,  // = in_deg8 (in place)
    const float* __restrict__ norm_out, int2* __restrict__ csr_sw, int E,
    const float* __restrict__ e0, const float* __restrict__ b0, const float* __restrict__ s0,
    const _Float16* __restrict__ WhE, const _Float16* __restrict__ WhB,
    const _Float16* __restrict__ WhS, const float* __restrict__ bBl,
    const float* __restrict__ sBl, _Float16* __restrict__ Q, int N, int FB, int GB) {
  int bx = blockIdx.x;
  if (bx < FB) {  // csr fill first (longest pole starts earliest)
    int e = bx * 256 + threadIdx.x;
    if (e < E) {
      int d = dst[e], s = src[e];
      int h = e & 7;  // must match deg_wcvt's h
      int pos = bin_base[h * N + d] + rank8[e];
      csr_sw[pos] = make_int2(s, __float_as_int(norm_out[s]));
    }
  } else {
    int gb = bx - FB;
    int part = gb / GB, rb = gb % GB;
    const float* A = (part == 0) ? e0 : (part == 1 ? b0 : s0);
    const _Float16* Wh = (part == 0) ? WhE : (part == 1 ? WhB : WhS);
    const float* Bb = (part == 0) ? nullptr : (part == 1 ? bBl : sBl);
    gemm0_tile(part, rb, A, Wh, Bb, Q, N);
  }
}

// standalone fp16 GEMM for layers >= 1
__global__ __launch_bounds__(256) void gemm3_kernel(const _Float16* __restrict__ P,
                                                    const _Float16* __restrict__ WhE,
                                                    const _Float16* __restrict__ WhB,
                                                    const _Float16* __restrict__ WhS,
                                                    const float* __restrict__ bBl,
                                                    const float* __restrict__ sBl,
                                                    _Float16* __restrict__ Q, int N) {
  int part = blockIdx.y;
  const _Float16* Wh = (part == 0) ? WhE : (part == 1 ? WhB : WhS);
  const float* Bb = (part == 0) ? nullptr : (part == 1 ? bBl : sBl);
  gemm_tile(part, blockIdx.x, P, Wh, Bb, Q, N);
}

// Fused gather over packed Q: one wave per dst node.
// Lane = 16*g + q : group g handles neighbor slot i+g, lane loads 16B (dims 8q..8q+7).
__global__ __launch_bounds__(256) void agg_fused_kernel(
    const _Float16* __restrict__ Q, const int* __restrict__ row_off,
    const int2* __restrict__ csr_sw, const float* __restrict__ norm_in,
    const float* __restrict__ inv_in, const float* __restrict__ eBias,
    float* __restrict__ oe, float* __restrict__ ob, float* __restrict__ os,
    _Float16* __restrict__ Pnext, int N, int write_pack, int write_out) {
  int lane = threadIdx.x & 63;
  int v = blockIdx.x * 4 + (threadIdx.x >> 6);
  if (v >= N) return;
  int g = lane >> 4, q = lane & 15;
  int beg = row_off[v], end = row_off[v + 1];
  float eacc[8], bacc[8], sacc[8];
#pragma unroll
  for (int j = 0; j < 8; ++j) { eacc[j] = 0.f; bacc[j] = 0.f; sacc[j] = 0.f; }
  int i = beg;
  for (; i + 8 <= end; i += 8) {  // 8 neighbors/iter, 6 x 16B gathers in flight
    int2 swa = csr_sw[i + g];
    int2 swb = csr_sw[i + 4 + g];
    float wa = __int_as_float(swa.y), wb = __int_as_float(swb.y);
    const _Float16* ra = Q + (size_t)swa.x * PSTRIDE + q * 8;
    const _Float16* rb = Q + (size_t)swb.x * PSTRIDE + q * 8;
    half8 ea = *(const half8*)ra;
    half8 e2 = *(const half8*)rb;
    half8 ba = *(const half8*)(ra + 128);
    half8 b2 = *(const half8*)(rb + 128);
    half8 sa = *(const half8*)(ra + 256);
    half8 s2 = *(const half8*)(rb + 256);
#pragma unroll
    for (int j = 0; j < 8; ++j) {
      eacc[j] += wa * (float)ea[j];
      eacc[j] += wb * (float)e2[j];
      bacc[j] += (float)ba[j];
      bacc[j] += (float)b2[j];
      sacc[j] += (float)sa[j];
      sacc[j] += (float)s2[j];
    }
  }
  if (i + 4 <= end) {
    int2 sw = csr_sw[i + g];
    float wgt = __int_as_float(sw.y);
    const _Float16* rp = Q + (size_t)sw.x * PSTRIDE + q * 8;
    half8 ev = *(const half8*)rp;
    half8 bv = *(const half8*)(rp + 128);
    half8 sv = *(const half8*)(rp + 256);
#pragma unroll
    for (int j = 0; j < 8; ++j) {
      eacc[j] += wgt * (float)ev[j];
      bacc[j] += (float)bv[j];
      sacc[j] += (float)sv[j];
    }
    i += 4;
  }
  if (i + g < end) {
    int2 sw = csr_sw[i + g];
    float wgt = __int_as_float(sw.y);
    const _Float16* rp = Q + (size_t)sw.x * PSTRIDE + q * 8;
    half8 ev = *(const half8*)rp;
    half8 bv = *(const half8*)(rp + 128);
    half8 sv = *(const half8*)(rp + 256);
#pragma unroll
    for (int j = 0; j < 8; ++j) {
      eacc[j] += wgt * (float)ev[j];
      bacc[j] += (float)bv[j];
      sacc[j] += (float)sv[j];
    }
  }
#pragma unroll
  for (int j = 0; j < 8; ++j) {  // combine 4 neighbor-groups
    eacc[j] += __shfl_xor(eacc[j], 16, 64);
    eacc[j] += __shfl_xor(eacc[j], 32, 64);
    bacc[j] += __shfl_xor(bacc[j], 16, 64);
    bacc[j] += __shfl_xor(bacc[j], 32, 64);
    sacc[j] += __shfl_xor(sacc[j], 16, 64);
    sacc[j] += __shfl_xor(sacc[j], 32, 64);
  }
  float ni = norm_in[v], iv = inv_in[v];
  const float4* ebp = (const float4*)eBias;
  float4 eb0 = ebp[q * 2], eb1 = ebp[q * 2 + 1];
  float bias[8] = {eb0.x, eb0.y, eb0.z, eb0.w, eb1.x, eb1.y, eb1.z, eb1.w};
  float h[8], ub[8], us[8];
  float ss2 = 0.f;
#pragma unroll
  for (int j = 0; j < 8; ++j) {
    float t = eacc[j] * ni + bias[j];
    h[j] = t > 0.f ? t : 0.2f * t;
    ub[j] = bacc[j] * iv;                 // tangent mean (b)
    us[j] = sacc[j] * iv; ss2 += us[j] * us[j];
  }
  float ns = sqrtf(g16_sum(ss2));
  float fs = 1.0f / fmaxf(ns, 1e-12f);    // l2norm scale
  if (write_out) {  // final layer: fp32 outputs, split across lane-groups
    float bs2 = 0.f;
#pragma unroll
    for (int j = 0; j < 8; ++j) bs2 += ub[j] * ub[j];
    float nb = sqrtf(g16_sum(bs2));
    float fb = tanhf(nb) / fmaxf(nb, 1e-7f);  // expmap0
    if (g == 0) {
      float4* p = (float4*)(oe + (size_t)v * DD);
      p[q * 2]     = make_float4(h[0], h[1], h[2], h[3]);
      p[q * 2 + 1] = make_float4(h[4], h[5], h[6], h[7]);
    } else if (g == 1) {
      float4* p = (float4*)(ob + (size_t)v * DD);
      p[q * 2]     = make_float4(ub[0] * fb, ub[1] * fb, ub[2] * fb, ub[3] * fb);
      p[q * 2 + 1] = make_float4(ub[4] * fb, ub[5] * fb, ub[6] * fb, ub[7] * fb);
    } else if (g == 2) {
      float4* p = (float4*)(os + (size_t)v * DD);
      p[q * 2]     = make_float4(us[0] * fs, us[1] * fs, us[2] * fs, us[3] * fs);
      p[q * 2 + 1] = make_float4(us[4] * fs, us[5] * fs, us[6] * fs, us[7] * fs);
    }
  }
  if (write_pack) {  // non-final layers: fp16 pack only
    if (g == 3) {
      half8 he, hb, hs;
#pragma unroll
      for (int j = 0; j < 8; ++j) {
        he[j] = (_Float16)h[j];
        hb[j] = (_Float16)ub[j];
        hs[j] = (_Float16)(us[j] * fs);
      }
      _Float16* Pr = Pnext + (size_t)v * PSTRIDE + q * 8;
      *(half8*)&Pr[0]   = he;
      *(half8*)&Pr[128] = hb;
      *(half8*)&Pr[256] = hs;
    }
  }
}

extern "C" void kernel_launch(void* const* d_in, const int* in_sizes, int n_in,
                              void* d_out, int out_size, void* d_ws, size_t ws_size,
                              hipStream_t stream) {
  const float* e0 = (const float*)d_in[0];
  const float* b0 = (const float*)d_in[1];
  const float* s0 = (const float*)d_in[2];
  const float* eW = (const float*)d_in[3];
  const float* eB = (const float*)d_in[4];
  const float* bW = (const float*)d_in[5];
  const float* bB = (const float*)d_in[6];
  const float* sW = (const float*)d_in[7];
  const float* sB = (const float*)d_in[8];
  const int* src = (const int*)d_in[9];
  const int* dst = (const int*)d_in[10];
  int N = in_sizes[0] / DD;
  int E = in_sizes[9];
  int L = in_sizes[3] / (DD * DD);
  int LDD2 = L * DD * DD;

  char* w = (char*)d_ws;
  // [in_deg8 | out_deg8] contiguous -> single memset
  int* in_deg8  = (int*)w; w += (size_t)8 * N * 4;  // later becomes absolute bin bases
  int* out_deg8 = (int*)w; w += (size_t)8 * N * 4;
  int* rank8    = (int*)w; w += (size_t)E * 4;
  int* in_deg   = (int*)w; w += (size_t)N * 4;
  int* row_off  = (int*)w; w += (size_t)(N + 4) * 4;
  int* pscan    = (int*)w; w += (size_t)1024 * 4;
  int2* csr_sw  = (int2*)w; w += (size_t)E * 8;
  float* norm_in  = (float*)w; w += (size_t)N * 4;
  float* norm_out = (float*)w; w += (size_t)N * 4;
  float* inv_in   = (float*)w; w += (size_t)N * 4;
  w = (char*)(((size_t)w + 255) & ~(size_t)255);  // align
  _Float16* P = (_Float16*)w; w += (size_t)N * PSTRIDE * 2;
  _Float16* Q = (_Float16*)w; w += (size_t)N * PSTRIDE * 2;
  _Float16* Wh = (_Float16*)w; w += (size_t)3 * LDD2 * 2;
  _Float16* whE = Wh;
  _Float16* whB = Wh + LDD2;
  _Float16* whS = Wh + 2 * LDD2;

  float* oe = (float*)d_out;
  float* ob = oe + (size_t)N * DD;
  float* os = ob + (size_t)N * DD;

  int DB = (E + 255) / 256;
  int AB = (N + 3) / 4;
  int GB = (N + 63) / 64;
  int WB = (LDD2 + 255) / 256;
  int PB = (N + 255) / 256;

  hipMemsetAsync(d_ws, 0, (size_t)16 * N * 4, stream);  // deg bins only
  deg_wcvt_kernel<<<DB + WB, 256, 0, stream>>>(src, dst, out_deg8, in_deg8, rank8, E, N,
                                               eW, bW, sW, Wh, LDD2, DB);
  norms_psum_kernel<<<PB, 256, 0, stream>>>(in_deg8, out_deg8, in_deg,
                                            norm_in, norm_out, inv_in, pscan, N);
  part_scan_kernel<<<1, 256, 0, stream>>>(pscan, PB);
  local_scan_kernel<<<PB, 256, 0, stream>>>(in_deg, pscan, row_off, in_deg8, N, E);
  fill_gemm0_kernel<<<DB + 3 * GB, 256, 0, stream>>>(src, dst, rank8, in_deg8, norm_out,
                                                     csr_sw, E, e0, b0, s0,
                                                     whE, whB, whS, bB, sB, Q, N, DB, GB);
  agg_fused_kernel<<<AB, 256, 0, stream>>>(Q, row_off, csr_sw, norm_in, inv_in, eB,
                                           oe, ob, os, P, N,
                                           (L > 1) ? 1 : 0, (L == 1) ? 1 : 0);
  for (int l = 1; l < L; ++l) {
    size_t lo = (size_t)l * DD * DD;
    gemm3_kernel<<<dim3(GB, 3), 256, 0, stream>>>(P, whE + lo, whB + lo, whS + lo,
                                                  bB + (size_t)l * DD, sB + (size_t)l * DD, Q, N);
    agg_fused_kernel<<<AB, 256, 0, stream>>>(Q, row_off, csr_sw, norm_in, inv_in,
                                             eB + (size_t)l * DD, oe, ob, os, P, N,
                                             (l < L - 1) ? 1 : 0, (l == L - 1) ? 1 : 0);
  }
}